// Round 1
// baseline (421.370 us; speedup 1.0000x reference)
//
#include <hip/hip_runtime.h>
#include <hip/hip_bf16.h>
#include <cstdint>

// ---------------- types ----------------
typedef __attribute__((ext_vector_type(4))) float  floatx4;
typedef __attribute__((ext_vector_type(8))) __bf16 bf16x8;

#define OUT_F 4096
#define IN_F  4096
#define TOKENS 8192
#define NG 32

// fp32 -> bf16 round-to-nearest-even
__device__ __forceinline__ unsigned short f2bf(float f) {
    union { float f; unsigned int u; } v; v.f = f;
    unsigned int u = v.u;
    u += 0x7fffu + ((u >> 16) & 1u);
    return (unsigned short)(u >> 16);
}

// async global->LDS, 16B per lane. LDS dest must be wave-uniform base; HW
// writes lane data at base + lane*16. Global src is per-lane.
__device__ __forceinline__ void load_lds16(const void* gsrc, void* ldst) {
    __builtin_amdgcn_global_load_lds(
        (const __attribute__((address_space(1))) uint32_t*)gsrc,
        (__attribute__((address_space(3))) uint32_t*)ldst,
        16, 0, 0);
}

// ---------------- prep kernels ----------------
__global__ void dequant_w_kernel(const int* __restrict__ q,
                                 const float* __restrict__ sc,
                                 const float* __restrict__ zr,
                                 unsigned short* __restrict__ Wb) {
    int idx = blockIdx.x * 256 + threadIdx.x;   // one int4 (4 elems) per thread
    int e0 = idx << 2;
    int row = e0 >> 12;          // / 4096
    int col = e0 & 4095;
    int g = col >> 7;            // group of 128 (4 consecutive elems share group)
    float s = sc[(row << 5) + g];
    float z = zr[(row << 5) + g];
    int4 qv = *(const int4*)(q + e0);
    ushort4 o;
    o.x = f2bf(((float)qv.x - z) * s);
    o.y = f2bf(((float)qv.y - z) * s);
    o.z = f2bf(((float)qv.z - z) * s);
    o.w = f2bf(((float)qv.w - z) * s);
    *(ushort4*)(Wb + e0) = o;
}

__global__ void convert_x_kernel(const float* __restrict__ X,
                                 unsigned short* __restrict__ Xb) {
    int idx = blockIdx.x * 256 + threadIdx.x;   // 4 elems per thread
    int e0 = idx << 2;
    float4 xv = *(const float4*)(X + e0);
    ushort4 o;
    o.x = f2bf(xv.x); o.y = f2bf(xv.y); o.z = f2bf(xv.z); o.w = f2bf(xv.w);
    *(ushort4*)(Xb + e0) = o;
}

// ---------------- main GEMM (m97 structure) ----------------
// C[M][N] = Xb[M][K] * Wb[N][K]^T + bias.  128x128 tile, BK=64, 4 waves (2x2),
// each wave 64x64 = 4x4 mfma_f32_16x16x32_bf16 fragments.
__global__ __launch_bounds__(256) void gemm_bf16_bt(
    const unsigned short* __restrict__ Xb,   // [M][K] bf16
    const unsigned short* __restrict__ Wb,   // [N][K] bf16
    const float* __restrict__ bias,          // [N]
    float* __restrict__ C,                   // [M][N]
    int M, int N, int K)
{
    __shared__ __align__(16) unsigned short sA[128 * 64];
    __shared__ __align__(16) unsigned short sB[128 * 64];

    const int tid  = threadIdx.x;
    const int lane = tid & 63;
    const int wid  = tid >> 6;
    const int wr   = wid >> 1;      // wave row 0..1
    const int wc   = wid & 1;       // wave col 0..1

    const int bm = blockIdx.y * 128;
    const int bn = blockIdx.x * 128;

    floatx4 acc[4][4] = {};

    // staging lane geometry: one wave-instruction covers 8 rows x 64 cols (bf16)
    const int srow = lane >> 3;          // 0..7
    const int scol = (lane & 7) * 8;     // k offset in elems

    for (int k0 = 0; k0 < K; k0 += 64) {
        #pragma unroll
        for (int i = 0; i < 4; ++i) {
            int r0 = wid * 32 + i * 8;   // this wave stages rows [wid*32, +32)
            const unsigned short* gA = Xb + (size_t)(bm + r0 + srow) * K + (k0 + scol);
            load_lds16(gA, &sA[r0 * 64]);
            const unsigned short* gB = Wb + (size_t)(bn + r0 + srow) * K + (k0 + scol);
            load_lds16(gB, &sB[r0 * 64]);
        }
        asm volatile("s_waitcnt vmcnt(0)" ::: "memory");
        __syncthreads();

        #pragma unroll
        for (int kk = 0; kk < 2; ++kk) {
            bf16x8 af[4], bfr[4];
            const int kof = kk * 32 + (lane >> 4) * 8;
            #pragma unroll
            for (int m = 0; m < 4; ++m) {
                int row = wr * 64 + m * 16 + (lane & 15);
                af[m] = *(const bf16x8*)&sA[row * 64 + kof];
            }
            #pragma unroll
            for (int n = 0; n < 4; ++n) {
                int row = wc * 64 + n * 16 + (lane & 15);
                bfr[n] = *(const bf16x8*)&sB[row * 64 + kof];
            }
            #pragma unroll
            for (int m = 0; m < 4; ++m)
                #pragma unroll
                for (int n = 0; n < 4; ++n)
                    acc[m][n] = __builtin_amdgcn_mfma_f32_16x16x32_bf16(
                        af[m], bfr[n], acc[m][n], 0, 0, 0);
        }
        __syncthreads();
    }

    // epilogue: C/D layout col = lane&15, row = (lane>>4)*4 + j
    #pragma unroll
    for (int n = 0; n < 4; ++n) {
        int col = bn + wc * 64 + n * 16 + (lane & 15);
        float bv = bias[col];
        #pragma unroll
        for (int m = 0; m < 4; ++m) {
            int row0 = bm + wr * 64 + m * 16 + (lane >> 4) * 4;
            #pragma unroll
            for (int j = 0; j < 4; ++j) {
                C[(size_t)(row0 + j) * N + col] = acc[m][n][j] + bv;
            }
        }
    }
}

// ---------------- fallback (fp32, no workspace needed) ----------------
__global__ void fallback_gemm(const float* __restrict__ X,
                              const int* __restrict__ q,
                              const float* __restrict__ sc,
                              const float* __restrict__ zr,
                              const float* __restrict__ bias,
                              float* __restrict__ C) {
    __shared__ float sX[16][17];
    __shared__ float sW[16][17];
    int tx = threadIdx.x, ty = threadIdx.y;
    int row = blockIdx.y * 16 + ty;       // token
    int col = blockIdx.x * 16 + tx;       // out feature
    float acc = 0.f;
    for (int k0 = 0; k0 < IN_F; k0 += 16) {
        sX[ty][tx] = X[(size_t)row * IN_F + k0 + tx];
        int wrow = blockIdx.x * 16 + ty;
        int kc = k0 + tx;
        int g = kc >> 7;
        sW[ty][tx] = ((float)q[(size_t)wrow * IN_F + kc] - zr[wrow * NG + g]) * sc[wrow * NG + g];
        __syncthreads();
        #pragma unroll
        for (int kk = 0; kk < 16; ++kk) acc += sX[ty][kk] * sW[tx][kk];
        __syncthreads();
    }
    C[(size_t)row * OUT_F + col] = acc + bias[col];
}

// ---------------- launch ----------------
extern "C" void kernel_launch(void* const* d_in, const int* in_sizes, int n_in,
                              void* d_out, int out_size, void* d_ws, size_t ws_size,
                              hipStream_t stream) {
    const float* input  = (const float*)d_in[0];
    const int*   qweight= (const int*)d_in[1];
    const float* scales = (const float*)d_in[2];
    const float* zeros  = (const float*)d_in[3];
    const float* bias   = (const float*)d_in[4];
    float* out = (float*)d_out;

    const size_t needW = (size_t)OUT_F * IN_F * sizeof(unsigned short);   // 32 MB
    const size_t needX = (size_t)TOKENS * IN_F * sizeof(unsigned short);  // 64 MB

    if (ws_size >= needW + needX) {
        unsigned short* Wb = (unsigned short*)d_ws;
        unsigned short* Xb = (unsigned short*)((char*)d_ws + needW);

        dequant_w_kernel<<<(OUT_F * IN_F / 4) / 256, 256, 0, stream>>>(qweight, scales, zeros, Wb);
        convert_x_kernel<<<(TOKENS * IN_F / 4) / 256, 256, 0, stream>>>(input, Xb);

        dim3 grid(OUT_F / 128, TOKENS / 128);
        gemm_bf16_bt<<<grid, 256, 0, stream>>>(Xb, Wb, bias, out, TOKENS, OUT_F, IN_F);
    } else {
        dim3 blk(16, 16);
        dim3 grid(OUT_F / 16, TOKENS / 16);
        fallback_gemm<<<grid, blk, 0, stream>>>(input, qweight, scales, zeros, bias, out);
    }
}

// Round 2
// 320.866 us; speedup vs baseline: 1.3132x; 1.3132x over previous
//
#include <hip/hip_runtime.h>
#include <hip/hip_bf16.h>
#include <cstdint>

typedef __attribute__((ext_vector_type(4))) float  floatx4;
typedef __attribute__((ext_vector_type(8))) __bf16 bf16x8;

#define M_T 8192   // tokens
#define N_T 4096   // out features
#define K_T 4096   // in features
#define NG  32

// fp32 -> bf16 round-to-nearest-even
__device__ __forceinline__ unsigned short f2bf(float f) {
    union { float f; unsigned int u; } v; v.f = f;
    unsigned int u = v.u;
    u += 0x7fffu + ((u >> 16) & 1u);
    return (unsigned short)(u >> 16);
}

// async global->LDS, 16B per lane; LDS dest wave-uniform base + lane*16.
__device__ __forceinline__ void load_lds16(const void* gsrc, void* ldst) {
    __builtin_amdgcn_global_load_lds(
        (const __attribute__((address_space(1))) uint32_t*)gsrc,
        (__attribute__((address_space(3))) uint32_t*)ldst,
        16, 0, 0);
}

// ---------------- prep kernels (unchanged, passed R1) ----------------
__global__ void dequant_w_kernel(const int* __restrict__ q,
                                 const float* __restrict__ sc,
                                 const float* __restrict__ zr,
                                 unsigned short* __restrict__ Wb) {
    int idx = blockIdx.x * 256 + threadIdx.x;
    int e0 = idx << 2;
    int row = e0 >> 12;
    int col = e0 & 4095;
    int g = col >> 7;
    float s = sc[(row << 5) + g];
    float z = zr[(row << 5) + g];
    int4 qv = *(const int4*)(q + e0);
    ushort4 o;
    o.x = f2bf(((float)qv.x - z) * s);
    o.y = f2bf(((float)qv.y - z) * s);
    o.z = f2bf(((float)qv.z - z) * s);
    o.w = f2bf(((float)qv.w - z) * s);
    *(ushort4*)(Wb + e0) = o;
}

__global__ void convert_x_kernel(const float* __restrict__ X,
                                 unsigned short* __restrict__ Xb) {
    int idx = blockIdx.x * 256 + threadIdx.x;
    int e0 = idx << 2;
    float4 xv = *(const float4*)(X + e0);
    ushort4 o;
    o.x = f2bf(xv.x); o.y = f2bf(xv.y); o.z = f2bf(xv.z); o.w = f2bf(xv.w);
    *(ushort4*)(Xb + e0) = o;
}

// ---------------- 256x256 8-phase GEMM (T1+T2+T3+T4+T5) ----------------
// C[M][N] = Xb[M][K] * Wb[N][K]^T + bias.
// 8 waves (2M x 4N), BK=64, LDS 128 KiB = 2 bufs x (A:2 halves + B:2 halves) x 16 KiB.
// Per iteration: phases 0-3 compute K-tile 2t (buf0), 4-7 compute 2t+1 (buf1).
// Stage schedule (1 half-tile = 2 global_load_lds per phase):
//   ph0: buf1.A0<-tile(2t+1)  ph1: buf1.A1<-tile(2t+1)
//   ph2: buf0.B0<-tile(2t+2)  ph3: buf0.B1<-tile(2t+2)
//   ph4: buf0.A0<-tile(2t+2)  ph5: buf0.A1<-tile(2t+2)
//   ph6: buf1.B0<-tile(2t+3)  ph7: buf1.B1<-tile(2t+3)
// Safety: B-halves of a buffer are last READ at its first phase (frags held in
// regs); A-halves at its last phase. Every stage issue follows a barrier that
// post-dates the drained last read of its destination half.
// vmcnt(4) at ph3 (ensures buf1 complete: older than last 2 halves) and ph7
// (ensures buf0 complete). Counted, never 0 in-loop (T4).
__global__ __launch_bounds__(512, 2) void gemm256_8ph(
    const unsigned short* __restrict__ Xb,
    const unsigned short* __restrict__ Wb,
    const float* __restrict__ bias,
    float* __restrict__ C)
{
    __shared__ __align__(16) unsigned short lds[65536];   // 128 KiB
    char* ldsb = (char*)lds;

    const int tid  = threadIdx.x;
    const int lane = tid & 63;
    const int wid  = tid >> 6;
    const int wm   = wid >> 2;    // 0..1
    const int wn   = wid & 3;     // 0..3

    // T1: XCD-aware swizzle, nwg=512 (%8==0)
    int bid = blockIdx.x;
    int swz = (bid & 7) * 64 + (bid >> 3);
    const int bm = (swz & 31) * 256;   // 32 M-tiles
    const int bn = (swz >> 5) * 256;   // 16 N-tiles

    floatx4 acc[8][4] = {};

    const int klb = (lane >> 4) * 16;  // k-group byte offset within 128B row

    // stage one 128x64 half-tile: grow0 = global row base, k0 = k elem base,
    // LDS dest linear, global source pre-swizzled (rule #21 / m173).
    auto stage_half = [&](int buf, int isB, int half, int grow0, int k0,
                          const unsigned short* __restrict__ G) {
        char* base = ldsb + buf * 65536 + isB * 32768 + half * 16384;
        #pragma unroll
        for (int c = 0; c < 2; ++c) {
            int r  = c * 64 + wid * 8 + (lane >> 3);
            int cb = ((lane & 7) * 16) ^ ((lane >> 3) << 4);
            const char* src = (const char*)(G + (size_t)(grow0 + r) * K_T + k0) + cb;
            load_lds16(src, base + c * 8192 + wid * 1024);
        }
    };
    // swizzled ds_read of one bf16x8 fragment
    auto rdA = [&](int buf, int mf, int kb) -> bf16x8 {
        int r = mf * 16 + (lane & 15);
        int off = buf * 65536 + wm * 16384 + r * 128 + (kb ^ ((r & 7) << 4));
        return *(const bf16x8*)(ldsb + off);
    };
    auto rdB = [&](int buf, int nf, int kb) -> bf16x8 {
        int r = (wn & 1) * 64 + nf * 16 + (lane & 15);
        int off = buf * 65536 + 32768 + (wn >> 1) * 16384 + r * 128 + (kb ^ ((r & 7) << 4));
        return *(const bf16x8*)(ldsb + off);
    };

    // ---- prologue: buf0 <- tile0 (B,B,A,A), buf1.B <- tile1 (12 loads) ----
    stage_half(0, 1, 0, bn,       0,  Wb);
    stage_half(0, 1, 1, bn + 128, 0,  Wb);
    stage_half(0, 0, 0, bm,       0,  Xb);
    stage_half(0, 0, 1, bm + 128, 0,  Xb);
    stage_half(1, 1, 0, bn,       64, Wb);
    stage_half(1, 1, 1, bn + 128, 64, Wb);
    asm volatile("s_waitcnt vmcnt(4)" ::: "memory");   // buf0 landed
    asm volatile("" ::: "memory");
    __builtin_amdgcn_s_barrier();
    asm volatile("" ::: "memory");

    bf16x8 bfr[4][2];

    for (int t = 0; t < 32; ++t) {
        const int t1 = 2 * t + 1;
        const int t2 = (2 * t + 2 < 64) ? 2 * t + 2 : 63;   // clamped (last iter only)
        const int t3 = (2 * t + 3 < 64) ? 2 * t + 3 : 63;
        #pragma unroll
        for (int p = 0; p < 8; ++p) {
            const int cb = p >> 2;     // compute buffer
            const int q  = p & 3;      // quadrant: M-frags 2q, 2q+1

            // ds-load register subtiles for THIS phase
            if (q == 0) {
                #pragma unroll
                for (int nf = 0; nf < 4; ++nf)
                    #pragma unroll
                    for (int kk = 0; kk < 2; ++kk)
                        bfr[nf][kk] = rdB(cb, nf, kk * 64 + klb);
            }
            bf16x8 a[2][2];
            #pragma unroll
            for (int i = 0; i < 2; ++i)
                #pragma unroll
                for (int kk = 0; kk < 2; ++kk)
                    a[i][kk] = rdA(cb, 2 * q + i, kk * 64 + klb);

            // stage one half-tile (schedule in header comment)
            switch (p) {
                case 0: stage_half(1, 0, 0, bm,       t1 * 64, Xb); break;
                case 1: stage_half(1, 0, 1, bm + 128, t1 * 64, Xb); break;
                case 2: stage_half(0, 1, 0, bn,       t2 * 64, Wb); break;
                case 3: stage_half(0, 1, 1, bn + 128, t2 * 64, Wb); break;
                case 4: stage_half(0, 0, 0, bm,       t2 * 64, Xb); break;
                case 5: stage_half(0, 0, 1, bm + 128, t2 * 64, Xb); break;
                case 6: stage_half(1, 1, 0, bn,       t3 * 64, Wb); break;
                case 7: stage_half(1, 1, 1, bn + 128, t3 * 64, Wb); break;
            }

            asm volatile("" ::: "memory");
            __builtin_amdgcn_s_barrier();
            asm volatile("" ::: "memory");

            __builtin_amdgcn_s_setprio(1);
            #pragma unroll
            for (int i = 0; i < 2; ++i)
                #pragma unroll
                for (int nf = 0; nf < 4; ++nf)
                    #pragma unroll
                    for (int kk = 0; kk < 2; ++kk)
                        acc[2 * q + i][nf] = __builtin_amdgcn_mfma_f32_16x16x32_bf16(
                            a[i][kk], bfr[nf][kk], acc[2 * q + i][nf], 0, 0, 0);
            __builtin_amdgcn_s_setprio(0);

            if (q == 3)   // counted vmcnt: allow last 2 staged halves in flight
                asm volatile("s_waitcnt vmcnt(4)" ::: "memory");
            asm volatile("" ::: "memory");
            __builtin_amdgcn_s_barrier();
            asm volatile("" ::: "memory");
        }
    }

    // drain in-flight LDS stages before workgroup can exit (LDS dealloc hazard)
    asm volatile("s_waitcnt vmcnt(0)" ::: "memory");

    // epilogue: C/D layout col=lane&15, row=(lane>>4)*4+j
    #pragma unroll
    for (int nf = 0; nf < 4; ++nf) {
        int col = bn + wn * 64 + nf * 16 + (lane & 15);
        float bv = bias[col];
        #pragma unroll
        for (int mf = 0; mf < 8; ++mf) {
            int row0 = bm + wm * 128 + mf * 16 + (lane >> 4) * 4;
            #pragma unroll
            for (int j = 0; j < 4; ++j)
                C[(size_t)(row0 + j) * N_T + col] = acc[mf][nf][j] + bv;
        }
    }
}

// ---------------- fallback (fp32, no workspace needed) ----------------
__global__ void fallback_gemm(const float* __restrict__ X,
                              const int* __restrict__ q,
                              const float* __restrict__ sc,
                              const float* __restrict__ zr,
                              const float* __restrict__ bias,
                              float* __restrict__ C) {
    __shared__ float sX[16][17];
    __shared__ float sW[16][17];
    int tx = threadIdx.x, ty = threadIdx.y;
    int row = blockIdx.y * 16 + ty;
    int col = blockIdx.x * 16 + tx;
    float acc = 0.f;
    for (int k0 = 0; k0 < K_T; k0 += 16) {
        sX[ty][tx] = X[(size_t)row * K_T + k0 + tx];
        int wrow = blockIdx.x * 16 + ty;
        int kc = k0 + tx;
        int g = kc >> 7;
        sW[ty][tx] = ((float)q[(size_t)wrow * K_T + kc] - zr[wrow * NG + g]) * sc[wrow * NG + g];
        __syncthreads();
        #pragma unroll
        for (int kk = 0; kk < 16; ++kk) acc += sX[ty][kk] * sW[tx][kk];
        __syncthreads();
    }
    C[(size_t)row * N_T + col] = acc + bias[col];
}

// ---------------- launch ----------------
extern "C" void kernel_launch(void* const* d_in, const int* in_sizes, int n_in,
                              void* d_out, int out_size, void* d_ws, size_t ws_size,
                              hipStream_t stream) {
    const float* input   = (const float*)d_in[0];
    const int*   qweight = (const int*)d_in[1];
    const float* scales  = (const float*)d_in[2];
    const float* zeros   = (const float*)d_in[3];
    const float* bias    = (const float*)d_in[4];
    float* out = (float*)d_out;

    const size_t needW = (size_t)N_T * K_T * sizeof(unsigned short);   // 32 MB
    const size_t needX = (size_t)M_T * K_T * sizeof(unsigned short);   // 64 MB

    if (ws_size >= needW + needX) {
        unsigned short* Wb = (unsigned short*)d_ws;
        unsigned short* Xb = (unsigned short*)((char*)d_ws + needW);

        dequant_w_kernel<<<(N_T * K_T / 4) / 256, 256, 0, stream>>>(qweight, scales, zeros, Wb);
        convert_x_kernel<<<(M_T * K_T / 4) / 256, 256, 0, stream>>>(input, Xb);

        gemm256_8ph<<<512, 512, 0, stream>>>(Xb, Wb, bias, out);
    } else {
        dim3 blk(16, 16);
        dim3 grid(N_T / 16, M_T / 16);
        fallback_gemm<<<grid, blk, 0, stream>>>(input, qweight, scales, zeros, bias, out);
    }
}

// Round 3
// 284.874 us; speedup vs baseline: 1.4791x; 1.1263x over previous
//
#include <hip/hip_runtime.h>
#include <hip/hip_bf16.h>
#include <cstdint>

typedef __attribute__((ext_vector_type(4))) float  floatx4;
typedef __attribute__((ext_vector_type(8))) __bf16 bf16x8;

#define M_T 8192   // tokens
#define N_T 4096   // out features
#define K_T 4096   // in features
#define NG  32

// fp32 -> bf16 round-to-nearest-even
__device__ __forceinline__ unsigned short f2bf(float f) {
    union { float f; unsigned int u; } v; v.f = f;
    unsigned int u = v.u;
    u += 0x7fffu + ((u >> 16) & 1u);
    return (unsigned short)(u >> 16);
}

// async global->LDS, 16B per lane; LDS dest wave-uniform base + lane*16.
__device__ __forceinline__ void load_lds16(const void* gsrc, void* ldst) {
    __builtin_amdgcn_global_load_lds(
        (const __attribute__((address_space(1))) uint32_t*)gsrc,
        (__attribute__((address_space(3))) uint32_t*)ldst,
        16, 0, 0);
}

// ---------------- prep kernels (unchanged, verified) ----------------
__global__ void dequant_w_kernel(const int* __restrict__ q,
                                 const float* __restrict__ sc,
                                 const float* __restrict__ zr,
                                 unsigned short* __restrict__ Wb) {
    int idx = blockIdx.x * 256 + threadIdx.x;
    int e0 = idx << 2;
    int row = e0 >> 12;
    int col = e0 & 4095;
    int g = col >> 7;
    float s = sc[(row << 5) + g];
    float z = zr[(row << 5) + g];
    int4 qv = *(const int4*)(q + e0);
    ushort4 o;
    o.x = f2bf(((float)qv.x - z) * s);
    o.y = f2bf(((float)qv.y - z) * s);
    o.z = f2bf(((float)qv.z - z) * s);
    o.w = f2bf(((float)qv.w - z) * s);
    *(ushort4*)(Wb + e0) = o;
}

__global__ void convert_x_kernel(const float* __restrict__ X,
                                 unsigned short* __restrict__ Xb) {
    int idx = blockIdx.x * 256 + threadIdx.x;
    int e0 = idx << 2;
    float4 xv = *(const float4*)(X + e0);
    ushort4 o;
    o.x = f2bf(xv.x); o.y = f2bf(xv.y); o.z = f2bf(xv.z); o.w = f2bf(xv.w);
    *(ushort4*)(Xb + e0) = o;
}

// ---------------- 256x256 8-phase GEMM (T1..T5, kk-split phases) ----------------
// C[M][N] = Xb[M][K] * Wb[N][K]^T + bias.
// 8 waves (2M x 4N), BK=64, LDS 128 KiB = 2 bufs x (A:2 halves + B:2 halves) x 16 KiB.
// Phases 0-3 compute K-tile 2t (buf0), 4-7 compute 2t+1 (buf1).
// Per-phase quadrant: q=p&3 -> (mf-half = q&1, kk = q>>1); 16 MFMA each.
// ds_read distribution: q0: B(kk0)x4 + A x4; q1: B(kk1)x4 prefetch + A x4;
// q2/q3: A x4.  (flattened from 12/4/4/4 to 8/8/4/4)
// Stage schedule (1 half-tile = 2 global_load_lds per phase):
//   ph0: buf1.A0<-t1  ph1: buf1.A1<-t1  ph2: buf0.B0<-t2  ph3: buf0.B1<-t2
//   ph4: buf0.A0<-t2  ph5: buf0.A1<-t2  ph6: buf1.B0<-t3  ph7: buf1.B1<-t3
// Hazards: B last read at its q1 phase; explicit lgkmcnt(0) before that
// phase-end barrier makes the following B-stage safe. A last read at q3; the
// q3 MFMA's lgkm wait + barrier makes the following A-stage safe.
// vmcnt(4) at ph3 (buf1 complete) and ph7 (buf0 complete) — counted, never 0.
__global__ __launch_bounds__(512, 2) void gemm256_8ph(
    const unsigned short* __restrict__ Xb,
    const unsigned short* __restrict__ Wb,
    const float* __restrict__ bias,
    float* __restrict__ C)
{
    __shared__ __align__(16) unsigned short lds[65536];   // 128 KiB
    char* ldsb = (char*)lds;

    const int tid  = threadIdx.x;
    const int lane = tid & 63;
    const int wid  = tid >> 6;
    const int wm   = wid >> 2;    // 0..1
    const int wn   = wid & 3;     // 0..3

    // T1: 2D XCD-aware swizzle. grid=512 = 8 XCD regions of 8Mx8N tiles.
    int bid = blockIdx.x;
    int xcd = bid & 7, r0 = bid >> 3;
    int mt = (xcd >> 1) * 8 + (r0 & 7);
    int nt = (xcd & 1) * 8 + (r0 >> 3);
    const int bm = mt * 256;
    const int bn = nt * 256;

    floatx4 acc[8][4] = {};

    const int klb = (lane >> 4) * 16;  // k-group byte offset within 128B row

    auto stage_half = [&](int buf, int isB, int half, int grow0, int k0,
                          const unsigned short* __restrict__ G) {
        char* base = ldsb + buf * 65536 + isB * 32768 + half * 16384;
        #pragma unroll
        for (int c = 0; c < 2; ++c) {
            int r  = c * 64 + wid * 8 + (lane >> 3);
            int cb = ((lane & 7) * 16) ^ ((lane >> 3) << 4);
            const char* src = (const char*)(G + (size_t)(grow0 + r) * K_T + k0) + cb;
            load_lds16(src, base + c * 8192 + wid * 1024);
        }
    };
    auto rdA = [&](int buf, int mf, int kb) -> bf16x8 {
        int r = mf * 16 + (lane & 15);
        int off = buf * 65536 + wm * 16384 + r * 128 + (kb ^ ((r & 7) << 4));
        return *(const bf16x8*)(ldsb + off);
    };
    auto rdB = [&](int buf, int nf, int kb) -> bf16x8 {
        int r = (wn & 1) * 64 + nf * 16 + (lane & 15);
        int off = buf * 65536 + 32768 + (wn >> 1) * 16384 + r * 128 + (kb ^ ((r & 7) << 4));
        return *(const bf16x8*)(ldsb + off);
    };

    // ---- prologue: buf0 <- tile0 (B,B,A,A), buf1.B <- tile1 ----
    stage_half(0, 1, 0, bn,       0,  Wb);
    stage_half(0, 1, 1, bn + 128, 0,  Wb);
    stage_half(0, 0, 0, bm,       0,  Xb);
    stage_half(0, 0, 1, bm + 128, 0,  Xb);
    stage_half(1, 1, 0, bn,       64, Wb);
    stage_half(1, 1, 1, bn + 128, 64, Wb);
    asm volatile("s_waitcnt vmcnt(4)" ::: "memory");   // buf0 landed
    __builtin_amdgcn_s_barrier();

    bf16x8 bfr[4][2];

    for (int t = 0; t < 32; ++t) {
        const int t1 = 2 * t + 1;
        const int t2 = (2 * t + 2 < 64) ? 2 * t + 2 : 63;   // clamp (last iter)
        const int t3 = (2 * t + 3 < 64) ? 2 * t + 3 : 63;
        #pragma unroll
        for (int p = 0; p < 8; ++p) {
            const int cb    = p >> 2;      // compute buffer
            const int q     = p & 3;
            const int mbase = (q & 1) * 4; // mf block: 0..3 or 4..7
            const int kkp   = q >> 1;      // k sub-block of BK=64

            // ds-loads for THIS phase (+ B kk1 prefetch at q1)
            if (q == 0) {
                #pragma unroll
                for (int nf = 0; nf < 4; ++nf)
                    bfr[nf][0] = rdB(cb, nf, klb);
            }
            if (q == 1) {
                #pragma unroll
                for (int nf = 0; nf < 4; ++nf)
                    bfr[nf][1] = rdB(cb, nf, 64 + klb);
            }
            bf16x8 a[4];
            #pragma unroll
            for (int m = 0; m < 4; ++m)
                a[m] = rdA(cb, mbase + m, kkp * 64 + klb);

            // stage one half-tile (schedule in header comment)
            switch (p) {
                case 0: stage_half(1, 0, 0, bm,       t1 * 64, Xb); break;
                case 1: stage_half(1, 0, 1, bm + 128, t1 * 64, Xb); break;
                case 2: stage_half(0, 1, 0, bn,       t2 * 64, Wb); break;
                case 3: stage_half(0, 1, 1, bn + 128, t2 * 64, Wb); break;
                case 4: stage_half(0, 0, 0, bm,       t2 * 64, Xb); break;
                case 5: stage_half(0, 0, 1, bm + 128, t2 * 64, Xb); break;
                case 6: stage_half(1, 1, 0, bn,       t3 * 64, Wb); break;
                case 7: stage_half(1, 1, 1, bn + 128, t3 * 64, Wb); break;
            }

            __builtin_amdgcn_s_barrier();

            __builtin_amdgcn_s_setprio(1);
            #pragma unroll
            for (int m = 0; m < 4; ++m)
                #pragma unroll
                for (int nf = 0; nf < 4; ++nf)
                    acc[mbase + m][nf] = __builtin_amdgcn_mfma_f32_16x16x32_bf16(
                        a[m], bfr[nf][kkp], acc[mbase + m][nf], 0, 0, 0);
            __builtin_amdgcn_s_setprio(0);

            if (q == 1)   // drain B(kk1) prefetch before next phase stages B
                asm volatile("s_waitcnt lgkmcnt(0)" ::: "memory");
            if (q == 3)   // counted vmcnt: buf for next 4 phases complete
                asm volatile("s_waitcnt vmcnt(4)" ::: "memory");
            __builtin_amdgcn_s_barrier();
        }
    }

    // drain in-flight LDS stages before workgroup exit
    asm volatile("s_waitcnt vmcnt(0)" ::: "memory");

    // epilogue: C/D layout col=lane&15, row=(lane>>4)*4+j
    #pragma unroll
    for (int nf = 0; nf < 4; ++nf) {
        int col = bn + wn * 64 + nf * 16 + (lane & 15);
        float bv = bias[col];
        #pragma unroll
        for (int mf = 0; mf < 8; ++mf) {
            int row0 = bm + wm * 128 + mf * 16 + (lane >> 4) * 4;
            #pragma unroll
            for (int j = 0; j < 4; ++j)
                C[(size_t)(row0 + j) * N_T + col] = acc[mf][nf][j] + bv;
        }
    }
}

// ---------------- fallback (fp32, no workspace needed) ----------------
__global__ void fallback_gemm(const float* __restrict__ X,
                              const int* __restrict__ q,
                              const float* __restrict__ sc,
                              const float* __restrict__ zr,
                              const float* __restrict__ bias,
                              float* __restrict__ C) {
    __shared__ float sX[16][17];
    __shared__ float sW[16][17];
    int tx = threadIdx.x, ty = threadIdx.y;
    int row = blockIdx.y * 16 + ty;
    int col = blockIdx.x * 16 + tx;
    float acc = 0.f;
    for (int k0 = 0; k0 < K_T; k0 += 16) {
        sX[ty][tx] = X[(size_t)row * K_T + k0 + tx];
        int wrow = blockIdx.x * 16 + ty;
        int kc = k0 + tx;
        int g = kc >> 7;
        sW[ty][tx] = ((float)q[(size_t)wrow * K_T + kc] - zr[wrow * NG + g]) * sc[wrow * NG + g];
        __syncthreads();
        #pragma unroll
        for (int kk = 0; kk < 16; ++kk) acc += sX[ty][kk] * sW[tx][kk];
        __syncthreads();
    }
    C[(size_t)row * N_T + col] = acc + bias[col];
}

// ---------------- launch ----------------
extern "C" void kernel_launch(void* const* d_in, const int* in_sizes, int n_in,
                              void* d_out, int out_size, void* d_ws, size_t ws_size,
                              hipStream_t stream) {
    const float* input   = (const float*)d_in[0];
    const int*   qweight = (const int*)d_in[1];
    const float* scales  = (const float*)d_in[2];
    const float* zeros   = (const float*)d_in[3];
    const float* bias    = (const float*)d_in[4];
    float* out = (float*)d_out;

    const size_t needW = (size_t)N_T * K_T * sizeof(unsigned short);   // 32 MB
    const size_t needX = (size_t)M_T * K_T * sizeof(unsigned short);   // 64 MB

    if (ws_size >= needW + needX) {
        unsigned short* Wb = (unsigned short*)d_ws;
        unsigned short* Xb = (unsigned short*)((char*)d_ws + needW);

        dequant_w_kernel<<<(N_T * K_T / 4) / 256, 256, 0, stream>>>(qweight, scales, zeros, Wb);
        convert_x_kernel<<<(M_T * K_T / 4) / 256, 256, 0, stream>>>(input, Xb);

        gemm256_8ph<<<512, 512, 0, stream>>>(Xb, Wb, bias, out);
    } else {
        dim3 blk(16, 16);
        dim3 grid(N_T / 16, M_T / 16);
        fallback_gemm<<<grid, blk, 0, stream>>>(input, qweight, scales, zeros, bias, out);
    }
}

// Round 4
// 277.461 us; speedup vs baseline: 1.5187x; 1.0267x over previous
//
#include <hip/hip_runtime.h>
#include <hip/hip_bf16.h>
#include <cstdint>

typedef __attribute__((ext_vector_type(4))) float  floatx4;
typedef __attribute__((ext_vector_type(8))) __bf16 bf16x8;

#define M_T 8192   // tokens
#define N_T 4096   // out features
#define K_T 4096   // in features
#define NG  32

// fp32 -> bf16 round-to-nearest-even
__device__ __forceinline__ unsigned short f2bf(float f) {
    union { float f; unsigned int u; } v; v.f = f;
    unsigned int u = v.u;
    u += 0x7fffu + ((u >> 16) & 1u);
    return (unsigned short)(u >> 16);
}

// async global->LDS, 16B per lane; LDS dest wave-uniform base + lane*16.
__device__ __forceinline__ void load_lds16(const void* gsrc, void* ldst) {
    __builtin_amdgcn_global_load_lds(
        (const __attribute__((address_space(1))) uint32_t*)gsrc,
        (__attribute__((address_space(3))) uint32_t*)ldst,
        16, 0, 0);
}

// ---------------- prep kernels (unchanged, verified) ----------------
__global__ void dequant_w_kernel(const int* __restrict__ q,
                                 const float* __restrict__ sc,
                                 const float* __restrict__ zr,
                                 unsigned short* __restrict__ Wb) {
    int idx = blockIdx.x * 256 + threadIdx.x;
    int e0 = idx << 2;
    int row = e0 >> 12;
    int col = e0 & 4095;
    int g = col >> 7;
    float s = sc[(row << 5) + g];
    float z = zr[(row << 5) + g];
    int4 qv = *(const int4*)(q + e0);
    ushort4 o;
    o.x = f2bf(((float)qv.x - z) * s);
    o.y = f2bf(((float)qv.y - z) * s);
    o.z = f2bf(((float)qv.z - z) * s);
    o.w = f2bf(((float)qv.w - z) * s);
    *(ushort4*)(Wb + e0) = o;
}

__global__ void convert_x_kernel(const float* __restrict__ X,
                                 unsigned short* __restrict__ Xb) {
    int idx = blockIdx.x * 256 + threadIdx.x;
    int e0 = idx << 2;
    float4 xv = *(const float4*)(X + e0);
    ushort4 o;
    o.x = f2bf(xv.x); o.y = f2bf(xv.y); o.z = f2bf(xv.z); o.w = f2bf(xv.w);
    *(ushort4*)(Xb + e0) = o;
}

// ---------------- 256x256 8-phase GEMM, 1-barrier phases + read-ahead ----------------
// C[M][N] = Xb[M][K] * Wb[N][K]^T + bias.
// 8 waves (2M x 4N), BK=64, LDS 128 KiB = 2 bufs x (A:2 halves + B:2 halves) x 16 KiB.
// Phases 0-3 compute buf0 (tile 2t), 4-7 compute buf1 (tile 2t+1).
// Phase q: mbase=(q&1)*4, kk=q>>1; 16 MFMA.
// Reads: q0-START: B[cb]kk0 x4 + A[cb]q0 x4 (critical). Tails: q0: B kk1 x4 +
// A(q1) x4; q1: A(q2) x4 (+lgkmcnt(0) drain); q2: A(q3) x4; q3: none.
// Stage schedule (unchanged): ph0:buf1.A0<-t1 ph1:buf1.A1<-t1 ph2:buf0.B0<-t2
// ph3:buf0.B1<-t2 ph4:buf0.A0<-t2 ph5:buf0.A1<-t2 ph6:buf1.B0<-t3 ph7:buf1.B1<-t3
// Hazard ledger (single end-of-phase barrier):
//  - every stage target's last reader drained >=1 barrier earlier (B reads
//    drain by FIFO before q0/q1 MFMA + q1 lgkmcnt(0); A tails drain before
//    consuming MFMA; then BAR separates).
//  - buf freshness: vmcnt(4)+BAR at q3 publishes the other buf (leaves only
//    the 4 newest B-stage loads in flight).
__global__ __launch_bounds__(512, 2) void gemm256_8ph(
    const unsigned short* __restrict__ Xb,
    const unsigned short* __restrict__ Wb,
    const float* __restrict__ bias,
    float* __restrict__ C)
{
    __shared__ __align__(16) unsigned short lds[65536];   // 128 KiB
    char* ldsb = (char*)lds;

    const int tid  = threadIdx.x;
    const int lane = tid & 63;
    const int wid  = tid >> 6;
    const int wm   = wid >> 2;    // 0..1
    const int wn   = wid & 3;     // 0..3

    // T1: 2D XCD-aware swizzle. grid=512 = 8 XCD regions of 8Mx8N tiles.
    int bid = blockIdx.x;
    int xcd = bid & 7, r0 = bid >> 3;
    int mt = (xcd >> 1) * 8 + (r0 & 7);
    int nt = (xcd & 1) * 8 + (r0 >> 3);
    const int bm = mt * 256;
    const int bn = nt * 256;

    floatx4 acc[8][4] = {};

    const int klb  = (lane >> 4) * 16;
    const int axor = (lane & 7) << 4;

    // precomputed 32-bit LDS byte offsets; all call-site indices compile-time
    int obA[2][2], obB[2][2];
    #pragma unroll
    for (int b = 0; b < 2; ++b)
        #pragma unroll
        for (int kp = 0; kp < 2; ++kp) {
            obA[b][kp] = b * 65536 + wm * 16384 + (lane & 15) * 128
                       + ((kp * 64 + klb) ^ axor);
            obB[b][kp] = b * 65536 + 32768 + (wn >> 1) * 16384 + (wn & 1) * 8192
                       + (lane & 15) * 128 + ((kp * 64 + klb) ^ axor);
        }

    auto rA = [&](int b, int kp, int mf) -> bf16x8 {
        return *(const bf16x8*)(ldsb + obA[b][kp] + mf * 2048);
    };
    auto rB = [&](int b, int kp, int nf) -> bf16x8 {
        return *(const bf16x8*)(ldsb + obB[b][kp] + nf * 2048);
    };

    // per-lane stage source byte offsets (c=0,1), uniform part added per call
    const int pl0 = (wid * 8 + (lane >> 3)) * 8192
                  + (((lane & 7) * 16) ^ ((lane >> 3) << 4));
    const int pl1 = pl0 + 64 * 8192;
    const char* GA = (const char*)Xb + (size_t)bm * 8192;
    const char* GB = (const char*)Wb + (size_t)bn * 8192;

    auto stage_half = [&](int buf, int isB, int half, int tk, const char* G) {
        char* dst = ldsb + buf * 65536 + isB * 32768 + half * 16384 + wid * 1024;
        const char* s0 = G + ((size_t)half * 1048576 + (size_t)tk * 128);
        load_lds16(s0 + pl0, dst);
        load_lds16(s0 + pl1, dst + 8192);
    };

    // ---- prologue: buf0 <- tile0 (B,B,A,A), buf1.B <- tile1 ----
    stage_half(0, 1, 0, 0, GB);
    stage_half(0, 1, 1, 0, GB);
    stage_half(0, 0, 0, 0, GA);
    stage_half(0, 0, 1, 0, GA);
    stage_half(1, 1, 0, 1, GB);
    stage_half(1, 1, 1, 1, GB);
    asm volatile("s_waitcnt vmcnt(4)" ::: "memory");   // buf0 landed
    __builtin_amdgcn_s_barrier();

    bf16x8 a[4], bfr[4][2];

    for (int t = 0; t < 32; ++t) {
        const int t1 = 2 * t + 1;
        const int t2 = (2 * t + 2 < 64) ? 2 * t + 2 : 63;   // clamp (last iter)
        const int t3 = (2 * t + 3 < 64) ? 2 * t + 3 : 63;
        #pragma unroll
        for (int p = 0; p < 8; ++p) {
            const int cb    = p >> 2;
            const int q     = p & 3;
            const int kkp   = q >> 1;
            const int mbase = (q & 1) * 4;

            // critical reads only at q0 (new buffer quadrant start)
            if (q == 0) {
                #pragma unroll
                for (int nf = 0; nf < 4; ++nf) bfr[nf][0] = rB(cb, 0, nf);
                #pragma unroll
                for (int m = 0; m < 4; ++m)    a[m] = rA(cb, 0, m);
            }

            switch (p) {
                case 0: stage_half(1, 0, 0, t1, GA); break;
                case 1: stage_half(1, 0, 1, t1, GA); break;
                case 2: stage_half(0, 1, 0, t2, GB); break;
                case 3: stage_half(0, 1, 1, t2, GB); break;
                case 4: stage_half(0, 0, 0, t2, GA); break;
                case 5: stage_half(0, 0, 1, t2, GA); break;
                case 6: stage_half(1, 1, 0, t3, GB); break;
                case 7: stage_half(1, 1, 1, t3, GB); break;
            }

            __builtin_amdgcn_s_setprio(1);
            #pragma unroll
            for (int m = 0; m < 4; ++m)
                #pragma unroll
                for (int nf = 0; nf < 4; ++nf)
                    acc[mbase + m][nf] = __builtin_amdgcn_mfma_f32_16x16x32_bf16(
                        a[m], bfr[nf][kkp], acc[mbase + m][nf], 0, 0, 0);
            __builtin_amdgcn_s_setprio(0);

            // tail reads (read-ahead for next phase, same compute buffer)
            if (q == 0) {
                #pragma unroll
                for (int nf = 0; nf < 4; ++nf) bfr[nf][1] = rB(cb, 1, nf);
            }
            if (q < 3) {
                const int qn = q + 1, kkn = qn >> 1, mbn = (qn & 1) * 4;
                #pragma unroll
                for (int m = 0; m < 4; ++m) a[m] = rA(cb, kkn, mbn + m);
            }

            if (q == 1)   // drain tails before B-stage of next phase (insurance)
                asm volatile("s_waitcnt lgkmcnt(0)" ::: "memory");
            if (q == 3)   // counted vmcnt: publish other buf (4 newest in flight)
                asm volatile("s_waitcnt vmcnt(4)" ::: "memory");
            __builtin_amdgcn_s_barrier();
        }
    }

    // drain in-flight LDS stages before workgroup exit
    asm volatile("s_waitcnt vmcnt(0)" ::: "memory");

    // epilogue: C/D layout col=lane&15, row=(lane>>4)*4+j
    #pragma unroll
    for (int nf = 0; nf < 4; ++nf) {
        int col = bn + wn * 64 + nf * 16 + (lane & 15);
        float bv = bias[col];
        #pragma unroll
        for (int mf = 0; mf < 8; ++mf) {
            int row0 = bm + wm * 128 + mf * 16 + (lane >> 4) * 4;
            #pragma unroll
            for (int j = 0; j < 4; ++j)
                C[(size_t)(row0 + j) * N_T + col] = acc[mf][nf][j] + bv;
        }
    }
}

// ---------------- fallback (fp32, no workspace needed) ----------------
__global__ void fallback_gemm(const float* __restrict__ X,
                              const int* __restrict__ q,
                              const float* __restrict__ sc,
                              const float* __restrict__ zr,
                              const float* __restrict__ bias,
                              float* __restrict__ C) {
    __shared__ float sX[16][17];
    __shared__ float sW[16][17];
    int tx = threadIdx.x, ty = threadIdx.y;
    int row = blockIdx.y * 16 + ty;
    int col = blockIdx.x * 16 + tx;
    float acc = 0.f;
    for (int k0 = 0; k0 < K_T; k0 += 16) {
        sX[ty][tx] = X[(size_t)row * K_T + k0 + tx];
        int wrow = blockIdx.x * 16 + ty;
        int kc = k0 + tx;
        int g = kc >> 7;
        sW[ty][tx] = ((float)q[(size_t)wrow * K_T + kc] - zr[wrow * NG + g]) * sc[wrow * NG + g];
        __syncthreads();
        #pragma unroll
        for (int kk = 0; kk < 16; ++kk) acc += sX[ty][kk] * sW[tx][kk];
        __syncthreads();
    }
    C[(size_t)row * N_T + col] = acc + bias[col];
}

// ---------------- launch ----------------
extern "C" void kernel_launch(void* const* d_in, const int* in_sizes, int n_in,
                              void* d_out, int out_size, void* d_ws, size_t ws_size,
                              hipStream_t stream) {
    const float* input   = (const float*)d_in[0];
    const int*   qweight = (const int*)d_in[1];
    const float* scales  = (const float*)d_in[2];
    const float* zeros   = (const float*)d_in[3];
    const float* bias    = (const float*)d_in[4];
    float* out = (float*)d_out;

    const size_t needW = (size_t)N_T * K_T * sizeof(unsigned short);   // 32 MB
    const size_t needX = (size_t)M_T * K_T * sizeof(unsigned short);   // 64 MB

    if (ws_size >= needW + needX) {
        unsigned short* Wb = (unsigned short*)d_ws;
        unsigned short* Xb = (unsigned short*)((char*)d_ws + needW);

        dequant_w_kernel<<<(N_T * K_T / 4) / 256, 256, 0, stream>>>(qweight, scales, zeros, Wb);
        convert_x_kernel<<<(M_T * K_T / 4) / 256, 256, 0, stream>>>(input, Xb);

        gemm256_8ph<<<512, 512, 0, stream>>>(Xb, Wb, bias, out);
    } else {
        dim3 blk(16, 16);
        dim3 grid(N_T / 16, M_T / 16);
        fallback_gemm<<<grid, blk, 0, stream>>>(input, qweight, scales, zeros, bias, out);
    }
}

// Round 5
// 276.829 us; speedup vs baseline: 1.5221x; 1.0023x over previous
//
#include <hip/hip_runtime.h>
#include <hip/hip_bf16.h>
#include <cstdint>

typedef __attribute__((ext_vector_type(4))) float  floatx4;
typedef __attribute__((ext_vector_type(8))) __bf16 bf16x8;

#define M_T 8192   // tokens
#define N_T 4096   // out features
#define K_T 4096   // in features
#define NG  32

// fp32 -> bf16 round-to-nearest-even
__device__ __forceinline__ unsigned short f2bf(float f) {
    union { float f; unsigned int u; } v; v.f = f;
    unsigned int u = v.u;
    u += 0x7fffu + ((u >> 16) & 1u);
    return (unsigned short)(u >> 16);
}

// async global->LDS, 16B per lane; LDS dest wave-uniform base + lane*16.
__device__ __forceinline__ void load_lds16(const void* gsrc, void* ldst) {
    __builtin_amdgcn_global_load_lds(
        (const __attribute__((address_space(1))) uint32_t*)gsrc,
        (__attribute__((address_space(3))) uint32_t*)ldst,
        16, 0, 0);
}

// ---------------- prep kernels (unchanged, verified) ----------------
__global__ void dequant_w_kernel(const int* __restrict__ q,
                                 const float* __restrict__ sc,
                                 const float* __restrict__ zr,
                                 unsigned short* __restrict__ Wb) {
    int idx = blockIdx.x * 256 + threadIdx.x;
    int e0 = idx << 2;
    int row = e0 >> 12;
    int col = e0 & 4095;
    int g = col >> 7;
    float s = sc[(row << 5) + g];
    float z = zr[(row << 5) + g];
    int4 qv = *(const int4*)(q + e0);
    ushort4 o;
    o.x = f2bf(((float)qv.x - z) * s);
    o.y = f2bf(((float)qv.y - z) * s);
    o.z = f2bf(((float)qv.z - z) * s);
    o.w = f2bf(((float)qv.w - z) * s);
    *(ushort4*)(Wb + e0) = o;
}

__global__ void convert_x_kernel(const float* __restrict__ X,
                                 unsigned short* __restrict__ Xb) {
    int idx = blockIdx.x * 256 + threadIdx.x;
    int e0 = idx << 2;
    float4 xv = *(const float4*)(X + e0);
    ushort4 o;
    o.x = f2bf(xv.x); o.y = f2bf(xv.y); o.z = f2bf(xv.z); o.w = f2bf(xv.w);
    *(ushort4*)(Xb + e0) = o;
}

// ---------------- 256x256 8-phase GEMM, full register read-ahead ----------------
// C[M][N] = Xb[M][K] * Wb[N][K]^T + bias.
// 8 waves (2M x 4N), BK=64, LDS 128 KiB = 2 bufs x (A 2 halves + B 2 halves) x 16 KiB.
// Phases 0-3 compute buf0 (tile 2t), 4-7 buf1 (tile 2t+1). Phase q: kk=q>>1,
// mbase=(q&1)*4; 16 MFMA, inputs preloaded at the PREVIOUS phase's tail:
//   q0-tail: bfr[][1]<-B kk1 (4) + a<-A kk0 mf4-7 (4)
//   q1-tail: a<-A kk1 mf0-3 (4)        q2-tail: a<-A kk1 mf4-7 (4)
//   q3-tail: bfr[][0]<-B' kk0 (4) + a<-A' kk0 mf0-3 (4)   (other buffer)
// Stage schedule: ph0:buf1.A0<-t1 ph1:buf1.A1<-t1 ph2:buf0.B0<-t2 ph3:buf0.B1<-t2
//                 ph4:buf0.A0<-t2 ph5:buf0.A1<-t2 ph6:buf1.B0<-t3 ph7:buf1.B1<-t3
// Waits: vmcnt(2) at ph2/ph6-end (publishes buf1/buf0: drains all but the
//   newest 2 loads; counted, never 0). lgkmcnt(4) at ph1/ph5-end (drains the
//   q0-tail B-kk1 reads before the next phase stages that B region; keeps the
//   4 fresh A reads in flight). Empty asm memory fence after every barrier so
//   no memory op crosses a barrier in either direction.
// Hazard ledger (per region): stage into X only after X's last reader drained
//   (lgkm) and >=1 barrier passed; read from X only after X's stages drained
//   (vmcnt counted) and >=1 barrier passed. Verified for all 8 stage slots.
__global__ __launch_bounds__(512, 2) void gemm256_8ph(
    const unsigned short* __restrict__ Xb,
    const unsigned short* __restrict__ Wb,
    const float* __restrict__ bias,
    float* __restrict__ C)
{
    __shared__ __align__(16) unsigned short lds[65536];   // 128 KiB
    char* ldsb = (char*)lds;

    const int tid  = threadIdx.x;
    const int lane = tid & 63;
    const int wid  = tid >> 6;
    const int wm   = wid >> 2;    // 0..1
    const int wn   = wid & 3;     // 0..3

    // T1: 2D XCD-aware swizzle. grid=512 = 8 XCD regions of 8Mx8N tiles.
    int bid = blockIdx.x;
    int xcd = bid & 7, r0 = bid >> 3;
    int mt = (xcd >> 1) * 8 + (r0 & 7);
    int nt = (xcd & 1) * 8 + (r0 >> 3);
    const int bm = mt * 256;
    const int bn = nt * 256;

    floatx4 acc[8][4] = {};

    const int klb  = (lane >> 4) * 16;
    const int axor = (lane & 7) << 4;

    int obA[2][2], obB[2][2];
    #pragma unroll
    for (int b = 0; b < 2; ++b)
        #pragma unroll
        for (int kp = 0; kp < 2; ++kp) {
            obA[b][kp] = b * 65536 + wm * 16384 + (lane & 15) * 128
                       + ((kp * 64 + klb) ^ axor);
            obB[b][kp] = b * 65536 + 32768 + (wn >> 1) * 16384 + (wn & 1) * 8192
                       + (lane & 15) * 128 + ((kp * 64 + klb) ^ axor);
        }

    auto rA = [&](int b, int kp, int mf) -> bf16x8 {
        return *(const bf16x8*)(ldsb + obA[b][kp] + mf * 2048);
    };
    auto rB = [&](int b, int kp, int nf) -> bf16x8 {
        return *(const bf16x8*)(ldsb + obB[b][kp] + nf * 2048);
    };

    const int pl0 = (wid * 8 + (lane >> 3)) * 8192
                  + (((lane & 7) * 16) ^ ((lane >> 3) << 4));
    const int pl1 = pl0 + 64 * 8192;
    const char* GA = (const char*)Xb + (size_t)bm * 8192;
    const char* GB = (const char*)Wb + (size_t)bn * 8192;

    auto stage_half = [&](int buf, int isB, int half, int tk, const char* G) {
        char* dst = ldsb + buf * 65536 + isB * 32768 + half * 16384 + wid * 1024;
        const char* s0 = G + ((size_t)half * 1048576 + (size_t)tk * 128);
        load_lds16(s0 + pl0, dst);
        load_lds16(s0 + pl1, dst + 8192);
    };

    // ---- prologue: buf0 <- tile0 (B,B,A,A), buf1.B <- tile1 ----
    stage_half(0, 1, 0, 0, GB);
    stage_half(0, 1, 1, 0, GB);
    stage_half(0, 0, 0, 0, GA);
    stage_half(0, 0, 1, 0, GA);
    stage_half(1, 1, 0, 1, GB);
    stage_half(1, 1, 1, 1, GB);
    asm volatile("s_waitcnt vmcnt(4)" ::: "memory");   // buf0 landed
    __builtin_amdgcn_s_barrier();
    asm volatile("" ::: "memory");

    bf16x8 a[4], bfr[4][2];
    // pre-read first phase's fragments (buf0 kk0)
    #pragma unroll
    for (int nf = 0; nf < 4; ++nf) bfr[nf][0] = rB(0, 0, nf);
    #pragma unroll
    for (int m = 0; m < 4; ++m)    a[m] = rA(0, 0, m);

    for (int t = 0; t < 32; ++t) {
        const int t1 = 2 * t + 1;
        const int t2 = (2 * t + 2 < 64) ? 2 * t + 2 : 63;   // clamp (last iter)
        const int t3 = (2 * t + 3 < 64) ? 2 * t + 3 : 63;
        #pragma unroll
        for (int p = 0; p < 8; ++p) {
            const int cb    = p >> 2;
            const int q     = p & 3;
            const int kkp   = q >> 1;
            const int mbase = (q & 1) * 4;

            switch (p) {
                case 0: stage_half(1, 0, 0, t1, GA); break;
                case 1: stage_half(1, 0, 1, t1, GA); break;
                case 2: stage_half(0, 1, 0, t2, GB); break;
                case 3: stage_half(0, 1, 1, t2, GB); break;
                case 4: stage_half(0, 0, 0, t2, GA); break;
                case 5: stage_half(0, 0, 1, t2, GA); break;
                case 6: stage_half(1, 1, 0, t3, GB); break;
                case 7: stage_half(1, 1, 1, t3, GB); break;
            }

            __builtin_amdgcn_s_setprio(1);
            #pragma unroll
            for (int m = 0; m < 4; ++m)
                #pragma unroll
                for (int nf = 0; nf < 4; ++nf)
                    acc[mbase + m][nf] = __builtin_amdgcn_mfma_f32_16x16x32_bf16(
                        a[m], bfr[nf][kkp], acc[mbase + m][nf], 0, 0, 0);
            __builtin_amdgcn_s_setprio(0);

            // tail reads: preload NEXT phase's fragments
            if (q == 0) {
                #pragma unroll
                for (int nf = 0; nf < 4; ++nf) bfr[nf][1] = rB(cb, 1, nf);
                #pragma unroll
                for (int m = 0; m < 4; ++m)    a[m] = rA(cb, 0, 4 + m);
            } else if (q == 1) {
                #pragma unroll
                for (int m = 0; m < 4; ++m)    a[m] = rA(cb, 1, m);
            } else if (q == 2) {
                #pragma unroll
                for (int m = 0; m < 4; ++m)    a[m] = rA(cb, 1, 4 + m);
            } else {
                const int nb = cb ^ 1;   // other buffer (published at q2-end)
                #pragma unroll
                for (int nf = 0; nf < 4; ++nf) bfr[nf][0] = rB(nb, 0, nf);
                #pragma unroll
                for (int m = 0; m < 4; ++m)    a[m] = rA(nb, 0, m);
            }

            if (q == 1)   // drain q0-tail B-kk1 reads before next B-stage
                asm volatile("s_waitcnt lgkmcnt(4)" ::: "memory");
            if (q == 2)   // publish other buffer: all but newest 2 loads drained
                asm volatile("s_waitcnt vmcnt(2)" ::: "memory");
            __builtin_amdgcn_s_barrier();
            asm volatile("" ::: "memory");
        }
    }

    // drain in-flight LDS stages before workgroup exit
    asm volatile("s_waitcnt vmcnt(0)" ::: "memory");

    // epilogue: C/D layout col=lane&15, row=(lane>>4)*4+j
    #pragma unroll
    for (int nf = 0; nf < 4; ++nf) {
        int col = bn + wn * 64 + nf * 16 + (lane & 15);
        float bv = bias[col];
        #pragma unroll
        for (int mf = 0; mf < 8; ++mf) {
            int row0 = bm + wm * 128 + mf * 16 + (lane >> 4) * 4;
            #pragma unroll
            for (int j = 0; j < 4; ++j)
                C[(size_t)(row0 + j) * N_T + col] = acc[mf][nf][j] + bv;
        }
    }
}

// ---------------- fallback (fp32, no workspace needed) ----------------
__global__ void fallback_gemm(const float* __restrict__ X,
                              const int* __restrict__ q,
                              const float* __restrict__ sc,
                              const float* __restrict__ zr,
                              const float* __restrict__ bias,
                              float* __restrict__ C) {
    __shared__ float sX[16][17];
    __shared__ float sW[16][17];
    int tx = threadIdx.x, ty = threadIdx.y;
    int row = blockIdx.y * 16 + ty;
    int col = blockIdx.x * 16 + tx;
    float acc = 0.f;
    for (int k0 = 0; k0 < K_T; k0 += 16) {
        sX[ty][tx] = X[(size_t)row * K_T + k0 + tx];
        int wrow = blockIdx.x * 16 + ty;
        int kc = k0 + tx;
        int g = kc >> 7;
        sW[ty][tx] = ((float)q[(size_t)wrow * K_T + kc] - zr[wrow * NG + g]) * sc[wrow * NG + g];
        __syncthreads();
        #pragma unroll
        for (int kk = 0; kk < 16; ++kk) acc += sX[ty][kk] * sW[tx][kk];
        __syncthreads();
    }
    C[(size_t)row * N_T + col] = acc + bias[col];
}

// ---------------- launch ----------------
extern "C" void kernel_launch(void* const* d_in, const int* in_sizes, int n_in,
                              void* d_out, int out_size, void* d_ws, size_t ws_size,
                              hipStream_t stream) {
    const float* input   = (const float*)d_in[0];
    const int*   qweight = (const int*)d_in[1];
    const float* scales  = (const float*)d_in[2];
    const float* zeros   = (const float*)d_in[3];
    const float* bias    = (const float*)d_in[4];
    float* out = (float*)d_out;

    const size_t needW = (size_t)N_T * K_T * sizeof(unsigned short);   // 32 MB
    const size_t needX = (size_t)M_T * K_T * sizeof(unsigned short);   // 64 MB

    if (ws_size >= needW + needX) {
        unsigned short* Wb = (unsigned short*)d_ws;
        unsigned short* Xb = (unsigned short*)((char*)d_ws + needW);

        dequant_w_kernel<<<(N_T * K_T / 4) / 256, 256, 0, stream>>>(qweight, scales, zeros, Wb);
        convert_x_kernel<<<(M_T * K_T / 4) / 256, 256, 0, stream>>>(input, Xb);

        gemm256_8ph<<<512, 512, 0, stream>>>(Xb, Wb, bias, out);
    } else {
        dim3 blk(16, 16);
        dim3 grid(N_T / 16, M_T / 16);
        fallback_gemm<<<grid, blk, 0, stream>>>(input, qweight, scales, zeros, bias, out);
    }
}